// Round 3
// baseline (347.162 us; speedup 1.0000x reference)
//
#include <hip/hip_runtime.h>

// out[b, t, h] = sum_{j=0..4} x[b, t+j, h] * attn[b, t+j]
// B=32, H=768, LENGTH=2048, PADDED=2052, fp32 in/out. Memory-bound streaming.
//
// R3: completes the 2x2 matrix {nt,cached} x {low ILP, deep ILP}:
//   nt+lowILP 108.5us (R0) | nt+deep 108.4us (R2)  -> nt path walls at 3.95 TB/s
//   cached+lowILP 125us, VGPR=36 (R1, latency-bound) | cached+deep = THIS.
// Cached x loads cut HBM traffic (R1 FETCH=107MB vs x=202MB: L3 served half;
// boundary overlap + cross-iteration reuse) and the explicit 8-deep phase
// split removes R1's proven ILP starvation (VGPR=36 -> 2-3 loads in flight).
// Stores stay nontemporal: out is write-once; cached stores would evict x
// from the 256 MB L3 (x+out = 403 MB > L3).

#define LEN     2048
#define WIDTH   5
#define PADDED  (LEN + WIDTH - 1)   // 2052
#define BATCH   32
#define HDIM    768
#define H4      (HDIM / 4)          // 192 float4 per row
#define TCHUNK  32
#define NCHUNK  (LEN / TCHUNK)      // 64
#define GRP     8                   // loads in flight per wave

typedef float vfloat4 __attribute__((ext_vector_type(4)));

__global__ __launch_bounds__(256) void widthap_kernel(
    const vfloat4* __restrict__ x,
    const float*   __restrict__ attn,
    vfloat4*       __restrict__ out)
{
    const int tid   = blockIdx.x * blockDim.x + threadIdx.x;
    const int h4    = tid % H4;            // lane-contiguous -> coalesced
    const int rest  = tid / H4;
    const int b     = rest % BATCH;
    const int chunk = rest / BATCH;
    const int t0 = chunk * TCHUNK;

    const vfloat4* xp = x    + ((size_t)b * PADDED + t0) * H4 + h4;
    const float*   ap = attn +  (size_t)b * PADDED + t0;
    vfloat4*       op = out  + ((size_t)b * LEN    + t0) * H4 + h4;

    // ring of pre-weighted values w[j] = x[t0+j]*attn[t0+j]
    vfloat4 w0, w1, w2, w3;
    {
        const float a0 = ap[0], a1 = ap[1], a2 = ap[2], a3 = ap[3];
        const vfloat4 v0 = xp[0 * (size_t)H4];
        const vfloat4 v1 = xp[1 * (size_t)H4];
        const vfloat4 v2 = xp[2 * (size_t)H4];
        const vfloat4 v3 = xp[3 * (size_t)H4];
        w0 = v0 * a0; w1 = v1 * a1; w2 = v2 * a2; w3 = v3 * a3;
    }

    #pragma unroll
    for (int g = 0; g < TCHUNK / GRP; ++g) {
        float   a[GRP];
        vfloat4 v[GRP];
        // phase 1a: attn scalars (wave-uniform addr, L1 broadcast hits)
        #pragma unroll
        for (int k = 0; k < GRP; ++k)
            a[k] = ap[g * GRP + k + 4];
        // phase 1b: 8 independent cached loads, all issued before any use
        #pragma unroll
        for (int k = 0; k < GRP; ++k)
            v[k] = xp[(size_t)(g * GRP + k + 4) * H4];
        // phase 2: weight, 5-tap sum, streaming store
        #pragma unroll
        for (int k = 0; k < GRP; ++k) {
            const vfloat4 w4 = v[k] * a[k];
            const vfloat4 s  = w0 + w1 + w2 + w3 + w4;
            __builtin_nontemporal_store(s, &op[(size_t)(g * GRP + k) * H4]);
            w0 = w1; w1 = w2; w2 = w3; w3 = w4;
        }
    }
}

extern "C" void kernel_launch(void* const* d_in, const int* in_sizes, int n_in,
                              void* d_out, int out_size, void* d_ws, size_t ws_size,
                              hipStream_t stream) {
    const vfloat4* x    = (const vfloat4*)d_in[0];  // (32,1,2052,768) fp32
    const float*   attn = (const float*)d_in[1];    // (32,2052) fp32
    vfloat4*       out  = (vfloat4*)d_out;          // (32,1,2048,768) fp32

    const int total_threads = H4 * BATCH * NCHUNK;    // 393216
    const int block = 256;
    const int grid  = total_threads / block;          // 1536 = 6 blocks/CU
    widthap_kernel<<<grid, block, 0, stream>>>(x, attn, out);
}

// Round 4
// 346.427 us; speedup vs baseline: 1.0021x; 1.0021x over previous
//
#include <hip/hip_runtime.h>

// out[b, t, h] = sum_{j=0..4} x[b, t+j, h] * attn[b, t+j]
// B=32, H=768, LENGTH=2048, PADDED=2052, fp32 in/out. Memory-bound streaming.
//
// R4: the R3 phase split was DEFEATED by the scheduler (VGPR=36 again -> 2-3
// loads in flight, latency-bound). This version forces it:
//  - sched_barrier(0) between the 8-load issue phase and the consume phase:
//    instruction order pinned, 8 global_load_dwordx4 in flight, 32 VGPRs
//    forcibly live. Proof-of-execution metric: VGPR_Count >= 60.
//  - attn reads scalarized: rest = tid/H4 is wave-uniform (192%64==0, waves
//    never straddle rows), asserted via readfirstlane -> attn goes through
//    s_load (lgkmcnt), OFF the in-order vmcnt FIFO; x/out bases become SGPR.
//  - x loads stay CACHED: L3 retains ~half the x stream across iterations
//    (R1/R3 FETCH=107-110 MB vs 227 MB of reads). nt loads pay full HBM and
//    wall at 3.96 TB/s (R0/R2, concurrency-independent).
//  - stores stay NT: out is write-once and must not evict x from the 256 MB L3.

#define LEN     2048
#define WIDTH   5
#define PADDED  (LEN + WIDTH - 1)   // 2052
#define BATCH   32
#define HDIM    768
#define H4      (HDIM / 4)          // 192 float4 per row
#define TCHUNK  32
#define NCHUNK  (LEN / TCHUNK)      // 64
#define GRP     8                   // forced loads-in-flight per wave

typedef float vfloat4 __attribute__((ext_vector_type(4)));

__global__ __launch_bounds__(256) void widthap_kernel(
    const vfloat4* __restrict__ x,
    const float*   __restrict__ attn,
    vfloat4*       __restrict__ out)
{
    const int tid  = blockIdx.x * blockDim.x + threadIdx.x;
    const int h4   = tid % H4;                                   // lane-contiguous
    const int rest = __builtin_amdgcn_readfirstlane(tid / H4);   // wave-uniform
    const int b     = rest % BATCH;
    const int chunk = rest / BATCH;
    const int t0    = chunk * TCHUNK;

    const vfloat4* xp = x    + ((size_t)b * PADDED + t0) * H4 + h4;
    const float*   ap = attn +  (size_t)b * PADDED + t0;         // SGPR base
    vfloat4*       op = out  + ((size_t)b * LEN    + t0) * H4 + h4;

    // ring of pre-weighted values w[j] = x[t0+j]*attn[t0+j]; each x read once
    vfloat4 w0, w1, w2, w3;
    {
        const float a0 = ap[0], a1 = ap[1], a2 = ap[2], a3 = ap[3]; // s_load
        const vfloat4 v0 = xp[0 * (size_t)H4];
        const vfloat4 v1 = xp[1 * (size_t)H4];
        const vfloat4 v2 = xp[2 * (size_t)H4];
        const vfloat4 v3 = xp[3 * (size_t)H4];
        w0 = v0 * a0; w1 = v1 * a1; w2 = v2 * a2; w3 = v3 * a3;
    }

    #pragma unroll
    for (int g = 0; g < TCHUNK / GRP; ++g) {
        vfloat4 v[GRP];
        // phase 1: 8 independent cached loads, order-pinned before any use
        #pragma unroll
        for (int k = 0; k < GRP; ++k)
            v[k] = xp[(size_t)(g * GRP + k + 4) * H4];
        __builtin_amdgcn_sched_barrier(0);   // nothing crosses: loads stay issued-early
        // phase 2: weight, 5-tap sum, streaming store (attn via s_load, off vmcnt)
        #pragma unroll
        for (int k = 0; k < GRP; ++k) {
            const float   ak = ap[g * GRP + k + 4];
            const vfloat4 w4 = v[k] * ak;
            const vfloat4 s  = w0 + w1 + w2 + w3 + w4;
            __builtin_nontemporal_store(s, &op[(size_t)(g * GRP + k) * H4]);
            w0 = w1; w1 = w2; w2 = w3; w3 = w4;
        }
    }
}

extern "C" void kernel_launch(void* const* d_in, const int* in_sizes, int n_in,
                              void* d_out, int out_size, void* d_ws, size_t ws_size,
                              hipStream_t stream) {
    const vfloat4* x    = (const vfloat4*)d_in[0];  // (32,1,2052,768) fp32
    const float*   attn = (const float*)d_in[1];    // (32,2052) fp32
    vfloat4*       out  = (vfloat4*)d_out;          // (32,1,2048,768) fp32

    const int total_threads = H4 * BATCH * NCHUNK;    // 393216
    const int block = 256;
    const int grid  = total_threads / block;          // 1536 = 6 blocks/CU
    widthap_kernel<<<grid, block, 0, stream>>>(x, attn, out);
}

// Round 5
// 335.504 us; speedup vs baseline: 1.0347x; 1.0326x over previous
//
#include <hip/hip_runtime.h>

// out[b, t, h] = sum_{j=0..4} x[b, t+j, h] * attn[b, t+j]
// B=32, H=768, LENGTH=2048, PADDED=2052, fp32 in/out. Memory-bound streaming.
//
// R5: store-path experiment. Evidence: both load paths are concurrency-
// insensitive throughput walls (nt 3.93 TB/s, cached ~3.4 TB/s effective);
// harness fill hits 6.6 TB/s write-only with PLAIN stores at 9.7% occupancy;
// every prior variant used NT stores. Bet: nt stores defeat L2 write
// coalescing (eager evict-first writebacks interleave with reads -> HBM R/W
// turnaround thrash); plain stores batch dirty lines in L2 (4 MB/XCD) like
// the fill does.
//  - x loads: NONTEMPORAL (fastest measured read path; keeps L2/L3 clean so
//    the store stream owns L2 for coalescing).
//  - out stores: PLAIN (the one untested axis).
//  - TCHUNK=64: nt reads pay full HBM, so minimize amplification (68/64).
//    grid=768 = 3 blocks/CU (proven equivalent to 6 blocks/CU here).
//  - attn scalarized (wave-uniform readfirstlane -> s_load, off vmcnt FIFO).

#define LEN     2048
#define WIDTH   5
#define PADDED  (LEN + WIDTH - 1)   // 2052
#define BATCH   32
#define HDIM    768
#define H4      (HDIM / 4)          // 192 float4 per row
#define TCHUNK  64
#define NCHUNK  (LEN / TCHUNK)      // 32

typedef float vfloat4 __attribute__((ext_vector_type(4)));

__global__ __launch_bounds__(256) void widthap_kernel(
    const vfloat4* __restrict__ x,
    const float*   __restrict__ attn,
    vfloat4*       __restrict__ out)
{
    const int tid  = blockIdx.x * blockDim.x + threadIdx.x;
    const int h4   = tid % H4;                                   // lane-contiguous
    const int rest = __builtin_amdgcn_readfirstlane(tid / H4);   // wave-uniform (192%64==0)
    const int b     = rest % BATCH;
    const int chunk = rest / BATCH;
    const int t0    = chunk * TCHUNK;

    const vfloat4* xp = x    + ((size_t)b * PADDED + t0) * H4 + h4;
    const float*   ap = attn +  (size_t)b * PADDED + t0;         // SGPR base -> s_load
    vfloat4*       op = out  + ((size_t)b * LEN    + t0) * H4 + h4;

    // ring of pre-weighted values w[j] = x[t0+j]*attn[t0+j]; each x read once
    vfloat4 w0, w1, w2, w3, w4;

    auto loadw = [&](int j) -> vfloat4 {
        const float   a = ap[j];                                        // scalar
        const vfloat4 v = __builtin_nontemporal_load(&xp[(size_t)j * H4]); // stream read
        return v * a;
    };

    w0 = loadw(0);
    w1 = loadw(1);
    w2 = loadw(2);
    w3 = loadw(3);

    #pragma unroll 8
    for (int i = 0; i < TCHUNK; ++i) {
        w4 = loadw(i + 4);
        const vfloat4 s = w0 + w1 + w2 + w3 + w4;
        op[(size_t)i * H4] = s;                       // PLAIN store: L2-coalesced
        w0 = w1; w1 = w2; w2 = w3; w3 = w4;
    }
}

extern "C" void kernel_launch(void* const* d_in, const int* in_sizes, int n_in,
                              void* d_out, int out_size, void* d_ws, size_t ws_size,
                              hipStream_t stream) {
    const vfloat4* x    = (const vfloat4*)d_in[0];  // (32,1,2052,768) fp32
    const float*   attn = (const float*)d_in[1];    // (32,2052) fp32
    vfloat4*       out  = (vfloat4*)d_out;          // (32,1,2048,768) fp32

    const int total_threads = H4 * BATCH * NCHUNK;    // 196608
    const int block = 256;
    const int grid  = total_threads / block;          // 768 = 3 blocks/CU
    widthap_kernel<<<grid, block, 0, stream>>>(x, attn, out);
}